// Round 1
// baseline (498.428 us; speedup 1.0000x reference)
//
#include <hip/hip_runtime.h>

// GenSP: B=4, C=64, H=W=256, stoken=16 -> nH=nW=16, nS=256, P=65536
// Output A: (B, nS, P) float32 = 256 MB, sparse: <=9 nonzeros per (b, :, p) column.
// M_COEF=0 -> grid channels are exactly zero -> ignore (Cf effectively 64).
// f2 (pixel norm) is constant across the 9 softmax candidates -> cancels.

#define BB 4
#define CC 64
#define HH 256
#define WW 256
#define NHB 16
#define NWB 16
#define NS 256
#define PP 65536

// ---------------- zero fill: d_out (256MB) + ws atomic targets ----------------
__global__ __launch_bounds__(256) void k_zero(float4* __restrict__ out4,
                                              float4* __restrict__ ws4) {
  long i = (long)blockIdx.x * 256 + threadIdx.x;
  out4[i] = make_float4(0.f, 0.f, 0.f, 0.f);
  if (i < 16896)  // num(65536) + den(1024) + c2_0(1024) floats = 16896 float4
    ws4[i] = make_float4(0.f, 0.f, 0.f, 0.f);
}

// ---------------- initial centroids: 16x16 block means + c2 ----------------
// grid: b(4) x bi(16) x cchunk(16, 4 channels each) = 1024 wgs of 256 threads
__global__ __launch_bounds__(256) void k_init_cent(const float* __restrict__ x,
                                                   float* __restrict__ cent0,
                                                   float* __restrict__ c2_0) {
  int wg = blockIdx.x;
  int cc = wg & 15;
  int bi = (wg >> 4) & 15;
  int b  = wg >> 8;
  int j = threadIdx.x;  // column 0..255 (coalesced)
  const float inv = 1.0f / 256.0f;
#pragma unroll
  for (int q = 0; q < 4; q++) {
    int c = cc * 4 + q;
    const float* xp = x + (((long)(b * CC + c) * HH + bi * 16) * WW) + j;
    float acc = 0.f;
#pragma unroll
    for (int i = 0; i < 16; i++) acc += xp[i * WW];
    // sum across the 16 lanes of each block-column
    for (int off = 8; off >= 1; off >>= 1) acc += __shfl_down(acc, off, 16);
    if ((j & 15) == 0) {
      float m = acc * inv;
      int s = bi * 16 + (j >> 4);
      cent0[(b * CC + c) * NS + s] = m;
      atomicAdd(&c2_0[b * NS + s], m * m);
    }
  }
}

// ---------------- shared affinity computation (per 16x16 block) ----------------
// Computes aff[9] for this thread's pixel. Candidates uniform per block.
// sidx[k]: >=0 valid superpixel index; <0 -> invalid, clamped idx = -1-sidx.

// ---------------- iter1: affinity + num/den accumulation ----------------
__global__ __launch_bounds__(256) void k_iter1(const float* __restrict__ x,
                                               const float* __restrict__ cent,
                                               const float* __restrict__ c2,
                                               float* __restrict__ num,
                                               float* __restrict__ den) {
  __shared__ float cent_s[9 * 64];
  __shared__ float c2_s[9];
  __shared__ int sidx[9];
  __shared__ float aff_s[256 * 9];

  int wg = blockIdx.x;
  int bj = wg & 15, bi = (wg >> 4) & 15, b = wg >> 8;
  int t = threadIdx.x;

  if (t < 9) {
    int di = t / 3 - 1, dj = t % 3 - 1;
    int ci = bi + di, cj = bj + dj;
    int cic = min(max(ci, 0), 15), cjc = min(max(cj, 0), 15);
    int s = cic * 16 + cjc;
    bool valid = (ci >= 0) && (ci < 16) && (cj >= 0) && (cj < 16);
    sidx[t] = valid ? s : (-1 - s);
    c2_s[t] = c2[b * NS + s];
  }
  for (int o = t; o < 576; o += 256) {
    int k = o >> 6, c = o & 63;
    int di = k / 3 - 1, dj = k % 3 - 1;
    int cic = min(max(bi + di, 0), 15), cjc = min(max(bj + dj, 0), 15);
    cent_s[k * 64 + c] = cent[(b * CC + c) * NS + cic * 16 + cjc];
  }
  __syncthreads();

  int il = t >> 4, jl = t & 15;
  int i = bi * 16 + il, j = bj * 16 + jl;
  const float* xp = x + (long)b * CC * PP + (long)i * WW + j;

  float acc[9];
#pragma unroll
  for (int k = 0; k < 9; k++) acc[k] = 0.f;
  for (int c = 0; c < 64; c++) {
    float v = xp[(long)c * PP];
#pragma unroll
    for (int k = 0; k < 9; k++) acc[k] += v * cent_s[k * 64 + c];
  }
  float lg[9], mx = -1e30f;
#pragma unroll
  for (int k = 0; k < 9; k++) {
    float l = 2.f * acc[k] - c2_s[k];  // -(c2 - 2*dot); f2 cancels in softmax
    l = (sidx[k] >= 0) ? l : -1e30f;
    lg[k] = l;
    mx = fmaxf(mx, l);
  }
  float e[9], sum = 0.f;
#pragma unroll
  for (int k = 0; k < 9; k++) {
    float ev = (sidx[k] >= 0) ? __expf(lg[k] - mx) : 0.f;
    e[k] = ev;
    sum += ev;
  }
  float rs = 1.f / sum;
#pragma unroll
  for (int k = 0; k < 9; k++) aff_s[t * 9 + k] = e[k] * rs;
  __syncthreads();

  // num[c, s_k] += sum_pix aff[pix][k] * x[c, pix];  den[s_k] += sum aff
  const float* xb = x + (long)b * CC * PP + (long)(bi * 16) * WW + bj * 16;
  for (int o = t; o < 585; o += 256) {
    float s_ = 0.f;
    if (o < 576) {
      int c = o / 9, k = o - c * 9;
      const float* xc = xb + (long)c * PP;
      for (int pix = 0; pix < 256; pix++)
        s_ += aff_s[pix * 9 + k] * xc[(pix >> 4) * WW + (pix & 15)];
      int sk = sidx[k];
      sk = sk >= 0 ? sk : (-1 - sk);
      atomicAdd(&num[(b * CC + c) * NS + sk], s_);  // s_==0 if invalid
    } else {
      int k = o - 576;
      for (int pix = 0; pix < 256; pix++) s_ += aff_s[pix * 9 + k];
      int sk = sidx[k];
      sk = sk >= 0 ? sk : (-1 - sk);
      atomicAdd(&den[b * NS + sk], s_);
    }
  }
}

// ---------------- finalize: cent1 = num/(den+1e-16), c2_1 ----------------
__global__ __launch_bounds__(256) void k_finalize(const float* __restrict__ num,
                                                  const float* __restrict__ den,
                                                  float* __restrict__ cent1,
                                                  float* __restrict__ c21) {
  int idx = blockIdx.x * 256 + threadIdx.x;  // 0..1023 -> (b, s)
  int b = idx >> 8, s = idx & 255;
  float d = den[b * NS + s] + 1e-16f;
  float inv = 1.f / d;
  float c2acc = 0.f;
  for (int c = 0; c < 64; c++) {
    float m = num[(b * CC + c) * NS + s] * inv;
    cent1[(b * CC + c) * NS + s] = m;
    c2acc += m * m;
  }
  c21[idx] = c2acc;
}

// ---------------- iter2: affinity + scatter into dense A ----------------
__global__ __launch_bounds__(256) void k_iter2(const float* __restrict__ x,
                                               const float* __restrict__ cent,
                                               const float* __restrict__ c2,
                                               float* __restrict__ out) {
  __shared__ float cent_s[9 * 64];
  __shared__ float c2_s[9];
  __shared__ int sidx[9];

  int wg = blockIdx.x;
  int bj = wg & 15, bi = (wg >> 4) & 15, b = wg >> 8;
  int t = threadIdx.x;

  if (t < 9) {
    int di = t / 3 - 1, dj = t % 3 - 1;
    int ci = bi + di, cj = bj + dj;
    int cic = min(max(ci, 0), 15), cjc = min(max(cj, 0), 15);
    int s = cic * 16 + cjc;
    bool valid = (ci >= 0) && (ci < 16) && (cj >= 0) && (cj < 16);
    sidx[t] = valid ? s : (-1 - s);
    c2_s[t] = c2[b * NS + s];
  }
  for (int o = t; o < 576; o += 256) {
    int k = o >> 6, c = o & 63;
    int di = k / 3 - 1, dj = k % 3 - 1;
    int cic = min(max(bi + di, 0), 15), cjc = min(max(bj + dj, 0), 15);
    cent_s[k * 64 + c] = cent[(b * CC + c) * NS + cic * 16 + cjc];
  }
  __syncthreads();

  int il = t >> 4, jl = t & 15;
  int i = bi * 16 + il, j = bj * 16 + jl;
  const float* xp = x + (long)b * CC * PP + (long)i * WW + j;

  float acc[9];
#pragma unroll
  for (int k = 0; k < 9; k++) acc[k] = 0.f;
  for (int c = 0; c < 64; c++) {
    float v = xp[(long)c * PP];
#pragma unroll
    for (int k = 0; k < 9; k++) acc[k] += v * cent_s[k * 64 + c];
  }
  float lg[9], mx = -1e30f;
#pragma unroll
  for (int k = 0; k < 9; k++) {
    float l = 2.f * acc[k] - c2_s[k];
    l = (sidx[k] >= 0) ? l : -1e30f;
    lg[k] = l;
    mx = fmaxf(mx, l);
  }
  float e[9], sum = 0.f;
#pragma unroll
  for (int k = 0; k < 9; k++) {
    float ev = (sidx[k] >= 0) ? __expf(lg[k] - mx) : 0.f;
    e[k] = ev;
    sum += ev;
  }
  float rs = 1.f / sum;

  float* outp = out + (long)b * NS * PP + (long)i * WW + j;
#pragma unroll
  for (int k = 0; k < 9; k++) {
    int sk = sidx[k];
    if (sk >= 0) outp[(long)sk * PP] = e[k] * rs;  // skip invalid (never clobber)
  }
}

extern "C" void kernel_launch(void* const* d_in, const int* in_sizes, int n_in,
                              void* d_out, int out_size, void* d_ws, size_t ws_size,
                              hipStream_t stream) {
  const float* x = (const float*)d_in[0];
  float* out = (float*)d_out;
  float* ws = (float*)d_ws;

  // ws layout (floats): num[65536] den[1024] c2_0[1024] | c2_1[1024] cent0[65536] cent1[65536]
  float* num   = ws;
  float* den   = ws + 65536;
  float* c2_0  = ws + 66560;
  float* c2_1  = ws + 67584;
  float* cent0 = ws + 68608;
  float* cent1 = ws + 134144;

  k_zero<<<65536, 256, 0, stream>>>((float4*)out, (float4*)ws);
  k_init_cent<<<1024, 256, 0, stream>>>(x, cent0, c2_0);
  k_iter1<<<1024, 256, 0, stream>>>(x, cent0, c2_0, num, den);
  k_finalize<<<4, 256, 0, stream>>>(num, den, cent1, c2_1);
  k_iter2<<<1024, 256, 0, stream>>>(x, cent1, c2_1, out);
}

// Round 2
// 446.332 us; speedup vs baseline: 1.1167x; 1.1167x over previous
//
#include <hip/hip_runtime.h>

// GenSP: B=4, C=64, H=W=256, st=16 -> nH=nW=16, nS=256, P=65536
// out (B,nS,P) = 256MB, <=9 nonzeros per pixel column.
// M_COEF=0 -> grid channels zero; f2 cancels in softmax.
//
// ws float layout:
//   num_t  [0, 65536)        (b,s,c) transposed
//   den    [65536, 66560)
//   cent0  [66560, 132096)   (b,s,c) transposed
//   cent1  [132096, 197632)
//   aff    [197632, +2359296) layout (b,k,p)

#define PP 65536

// ---- init: block means -> cent0_t[(b*256+s)*64+c]; also zero num/den ----
__global__ __launch_bounds__(256) void k_init(const float* __restrict__ x,
                                              float* __restrict__ cent0,
                                              float4* __restrict__ zero4) {
  int t = threadIdx.x;
  int wg = blockIdx.x;                 // 256 = b(4) x bi(16) x cg(4)
  int cg = wg & 3, bi = (wg >> 2) & 15, b = wg >> 6;
  int tid = wg * 256 + t;
  if (tid < 16640) zero4[tid] = make_float4(0.f, 0.f, 0.f, 0.f);  // num+den
  int sub = t >> 6, j4 = t & 63;       // lane j4: 4 cols each
#pragma unroll
  for (int q = 0; q < 4; q++) {
    int c = cg * 16 + sub * 4 + q;
    const float4* xp4 = (const float4*)(x + (long)(b * 64 + c) * PP + (bi * 16) * 256 + j4 * 4);
    float4 a = make_float4(0.f, 0.f, 0.f, 0.f);
#pragma unroll
    for (int r = 0; r < 16; r++) {
      float4 v = xp4[r * 64];
      a.x += v.x; a.y += v.y; a.z += v.z; a.w += v.w;
    }
    float ps = a.x + a.y + a.z + a.w;
    ps += __shfl_xor(ps, 1);
    ps += __shfl_xor(ps, 2);
    if ((j4 & 3) == 0)
      cent0[((b << 8) + bi * 16 + (j4 >> 2)) * 64 + c] = ps * (1.f / 256.f);
  }
}

// ---- iter: strip = 8 rows x 64 cols (4 blocks), 2 px/thread ----
// mode 0: accumulate num_t/den (atomics). mode 1: write aff[b][k][p].
__global__ __launch_bounds__(256) void k_iter(const float* __restrict__ x,
                                              const float* __restrict__ cent,
                                              float* __restrict__ num,
                                              float* __restrict__ den,
                                              float* __restrict__ affout,
                                              int mode) {
  __shared__ float cent_s[18 * 68];  // 18 cents x 64 ch, stride 68 (bank pad)
  __shared__ float c2p[144];
  __shared__ float c2_s[18];
  __shared__ float red_s[2340];      // num_s[4][9][64] + den_s[4][9]

  int t = threadIdx.x;
  int wg = blockIdx.x;               // 512 = b(4) x bi(16) x sx(4) x half(2)
  int half = wg & 1, sx = (wg >> 1) & 3, bi = (wg >> 3) & 15, b = wg >> 7;

  for (int o = t; o < 2340; o += 256) red_s[o] = 0.f;

  // stage 18 centroids (rows bi-1..bi+1, cols sx*4-1..sx*4+4, clamped)
  for (int o = t; o < 288; o += 256) {
    int lc = o >> 4, f4i = o & 15;
    int ci = min(max(bi - 1 + lc / 6, 0), 15);
    int cj = min(max(sx * 4 - 1 + lc % 6, 0), 15);
    float4 v = *(const float4*)(cent + (((b << 8) + ci * 16 + cj) << 6) + f4i * 4);
    *(float4*)&cent_s[lc * 68 + f4i * 4] = v;
  }
  __syncthreads();
  if (t < 144) {
    int lc = t >> 3, pt = t & 7;
    float s = 0.f;
#pragma unroll
    for (int m = 0; m < 8; m++) { float v = cent_s[lc * 68 + pt * 8 + m]; s += v * v; }
    c2p[t] = s;
  }
  __syncthreads();
  if (t < 18) {
    float s = 0.f;
#pragma unroll
    for (int m = 0; m < 8; m++) s += c2p[t * 8 + m];
    c2_s[t] = s;
  }
  __syncthreads();

  int r = t >> 5, g = t & 31;
  int row = bi * 16 + half * 8 + r;
  int col = sx * 64 + g * 2;
  int lb = g >> 3;                   // local block 0..3
  int bjb = sx * 4 + lb;

  int cidx[9];
  float c2k[9];
  int vbits = 0;
#pragma unroll
  for (int k = 0; k < 9; k++) {
    int di = k / 3 - 1, dj = k % 3 - 1;
    int ciu = bi + di, cju = bjb + dj;
    if ((unsigned)ciu < 16u && (unsigned)cju < 16u) vbits |= 1 << k;
    int lidx = (di + 1) * 6 + (lb + 1 + dj);
    cidx[k] = lidx * 68;
    c2k[k] = c2_s[lidx];
  }

  const float* base = x + (long)(b * 64) * PP + row * 256 + col;

  float acc0[9], acc1[9];
#pragma unroll
  for (int k = 0; k < 9; k++) { acc0[k] = 0.f; acc1[k] = 0.f; }
#pragma unroll 4
  for (int c = 0; c < 64; c++) {
    float2 xv = *(const float2*)(base + ((long)c << 16));
#pragma unroll
    for (int k = 0; k < 9; k++) {
      float cv = cent_s[cidx[k] + c];
      acc0[k] = fmaf(xv.x, cv, acc0[k]);
      acc1[k] = fmaf(xv.y, cv, acc1[k]);
    }
  }

  // softmax (f2 term cancels); invalid logits -> -1e30 -> exp underflows to 0
  float mx0 = -1e30f, mx1 = -1e30f;
#pragma unroll
  for (int k = 0; k < 9; k++) {
    float l0 = 2.f * acc0[k] - c2k[k];
    float l1 = 2.f * acc1[k] - c2k[k];
    bool v = (vbits >> k) & 1;
    acc0[k] = v ? l0 : -1e30f;
    acc1[k] = v ? l1 : -1e30f;
    mx0 = fmaxf(mx0, acc0[k]);
    mx1 = fmaxf(mx1, acc1[k]);
  }
  float s0 = 0.f, s1 = 0.f;
#pragma unroll
  for (int k = 0; k < 9; k++) {
    acc0[k] = __expf(acc0[k] - mx0);
    acc1[k] = __expf(acc1[k] - mx1);
    s0 += acc0[k];
    s1 += acc1[k];
  }
  float rs0 = 1.f / s0, rs1 = 1.f / s1;
#pragma unroll
  for (int k = 0; k < 9; k++) { acc0[k] *= rs0; acc1[k] *= rs1; }

  if (mode == 1) {
    float* ap = affout + ((b * 9) << 16) + row * 256 + col;
#pragma unroll
    for (int k = 0; k < 9; k++)
      *(float2*)(ap + ((long)k << 16)) = make_float2(acc0[k], acc1[k]);
    return;
  }

  // ---- num/den accumulation ----
  int lane = t & 63;
  bool desig = (lane & 39) == 0;     // bits 0,1,2,5 clear -> lanes 0,8,16,24

  // den: weight-only pass
#pragma unroll
  for (int k = 0; k < 9; k++) {
    float w = acc0[k] + acc1[k];
    w += __shfl_xor(w, 1);
    w += __shfl_xor(w, 2);
    w += __shfl_xor(w, 4);
    w += __shfl_xor(w, 32);
    if (desig) atomicAdd(&red_s[2304 + lb * 9 + k], w);
  }
  // num: re-read x (coalesced, L2/HBM), reduce per (block, k, c)
#pragma unroll 2
  for (int c = 0; c < 64; c++) {
    float2 xv = *(const float2*)(base + ((long)c << 16));
#pragma unroll
    for (int k = 0; k < 9; k++) {
      float w = xv.x * acc0[k] + xv.y * acc1[k];
      w += __shfl_xor(w, 1);
      w += __shfl_xor(w, 2);
      w += __shfl_xor(w, 4);
      w += __shfl_xor(w, 32);
      if (desig) atomicAdd(&red_s[(lb * 9 + k) * 64 + c], w);
    }
  }
  __syncthreads();
  // flush to global (skip invalid candidates)
  for (int o = t; o < 2340; o += 256) {
    if (o < 2304) {
      int lb2 = o / 576, rm = o - lb2 * 576;
      int k = rm >> 6, c = rm & 63;
      int di = k / 3 - 1, dj = k % 3 - 1;
      int ciu = bi + di, cju = sx * 4 + lb2 + dj;
      if ((unsigned)ciu < 16u && (unsigned)cju < 16u)
        atomicAdd(&num[(((b << 8) + ciu * 16 + cju) << 6) + c], red_s[o]);
    } else {
      int idx = o - 2304;
      int lb2 = idx / 9, k = idx - lb2 * 9;
      int di = k / 3 - 1, dj = k % 3 - 1;
      int ciu = bi + di, cju = sx * 4 + lb2 + dj;
      if ((unsigned)ciu < 16u && (unsigned)cju < 16u)
        atomicAdd(&den[(b << 8) + ciu * 16 + cju], red_s[o]);
    }
  }
}

// ---- finalize: cent1 = num/(den+1e-16) ----
__global__ __launch_bounds__(256) void k_finalize(const float* __restrict__ num,
                                                  const float* __restrict__ den,
                                                  float* __restrict__ cent1) {
  int t = threadIdx.x;
  int c = t & 63, sl = t >> 6;
#pragma unroll 4
  for (int m = 0; m < 16; m++) {
    int bsl = (blockIdx.x << 6) + (m << 2) + sl;   // 16 wgs x 64 = 1024 (b,s)
    float d = den[bsl] + 1e-16f;
    cent1[(bsl << 6) + c] = num[(bsl << 6) + c] / d;
  }
}

// ---- writer: stream full 256MB output, zero or aff per element ----
__global__ __launch_bounds__(256) void k_writer(const float* __restrict__ aff,
                                                float4* __restrict__ out4) {
  int i4 = blockIdx.x * 256 + threadIdx.x;   // 16.7M float4
  int p4 = i4 & 16383;
  int s = (i4 >> 14) & 255;
  int b = i4 >> 22;
  int p0 = p4 << 2;
  int i = p0 >> 8, j = p0 & 255;
  int di = (s >> 4) - (i >> 4);
  int dj = (s & 15) - (j >> 4);
  float4 v = make_float4(0.f, 0.f, 0.f, 0.f);
  if ((unsigned)(di + 1) <= 2u && (unsigned)(dj + 1) <= 2u) {
    int k = (di + 1) * 3 + dj + 1;
    v = *(const float4*)(aff + (((b * 9 + k) << 16) + p0));
  }
  out4[i4] = v;
}

extern "C" void kernel_launch(void* const* d_in, const int* in_sizes, int n_in,
                              void* d_out, int out_size, void* d_ws, size_t ws_size,
                              hipStream_t stream) {
  const float* x = (const float*)d_in[0];
  float* out = (float*)d_out;
  float* ws = (float*)d_ws;

  float* num   = ws;
  float* den   = ws + 65536;
  float* cent0 = ws + 66560;
  float* cent1 = ws + 132096;
  float* aff   = ws + 197632;

  k_init<<<256, 256, 0, stream>>>(x, cent0, (float4*)ws);
  k_iter<<<512, 256, 0, stream>>>(x, cent0, num, den, nullptr, 0);
  k_finalize<<<16, 256, 0, stream>>>(num, den, cent1);
  k_iter<<<512, 256, 0, stream>>>(x, cent1, nullptr, nullptr, aff, 1);
  k_writer<<<65536, 256, 0, stream>>>(aff, (float4*)out);
}

// Round 3
// 441.437 us; speedup vs baseline: 1.1291x; 1.0111x over previous
//
#include <hip/hip_runtime.h>

// GenSP: B=4, C=64, H=W=256, st=16 -> nH=nW=16, nS=256, P=65536
// out (B,nS,P) = 256MB dense, <=9 nonzeros per pixel column.
// M_COEF=0 -> grid channels zero; f2 (pixel norm) cancels in softmax.
//
// 3-kernel chain: k_init (cent0 + zero num/den) -> k_stat (num/den via
// shfl-reduce + atomics) -> k_out (finalize cents in LDS + affinity + full
// coalesced 256MB output write).
//
// ws float layout: num[65536] den[1024] cent0[65536]

#define PP 65536

// ---- init: 16x16 block means -> cent0[(b*256+s)*64+c]; zero num/den ----
// grid 1024 = b(4) x bi(16) x cg(16 groups of 4 channels); 4 wg/CU.
__global__ __launch_bounds__(256) void k_init(const float* __restrict__ x,
                                              float* __restrict__ cent0,
                                              float4* __restrict__ zero4) {
  __shared__ float blk[64];  // [sj(16)][q(4)]
  int t = threadIdx.x;
  int wg = blockIdx.x;
  int cg = wg & 15, bi = (wg >> 4) & 15, b = wg >> 8;
  int tid = wg * 256 + t;
  if (tid < 16640) zero4[tid] = make_float4(0.f, 0.f, 0.f, 0.f);  // num+den
  if (t < 64) blk[t] = 0.f;
  __syncthreads();
  int sub = t >> 6, j4 = t & 63;  // rows sub*4..+3, float4-col j4
#pragma unroll
  for (int q = 0; q < 4; q++) {
    int c = cg * 4 + q;
    const float4* xp4 =
        (const float4*)(x + ((long)(b * 64 + c) << 16) + ((bi * 16 + sub * 4) << 8)) + j4;
    float4 a = make_float4(0.f, 0.f, 0.f, 0.f);
#pragma unroll
    for (int r = 0; r < 4; r++) {
      float4 v = xp4[r * 64];
      a.x += v.x; a.y += v.y; a.z += v.z; a.w += v.w;
    }
    float ps = a.x + a.y + a.z + a.w;
    ps += __shfl_xor(ps, 1);
    ps += __shfl_xor(ps, 2);
    if ((j4 & 3) == 0) atomicAdd(&blk[(j4 >> 2) * 4 + q], ps);
  }
  __syncthreads();
  if (t < 64) {
    int sj = t >> 2, q = t & 3;
    cent0[(((b << 8) + bi * 16 + sj) << 6) + cg * 4 + q] = blk[t] * (1.f / 256.f);
  }
}

// ---- stat: strip = 8 rows x 64 cols, 2 px/thread; num/den accumulation ----
__global__ __launch_bounds__(256) void k_stat(const float* __restrict__ x,
                                              const float* __restrict__ cent,
                                              float* __restrict__ num,
                                              float* __restrict__ den) {
  __shared__ float cent_s[18 * 68];
  __shared__ float c2p[144];
  __shared__ float c2_s[18];
  __shared__ float red_s[2340];  // num_s[4][9][64] + den_s[4][9]

  int t = threadIdx.x;
  int wg = blockIdx.x;  // 512 = b(4) x bi(16) x sx(4) x half(2)
  int half = wg & 1, sx = (wg >> 1) & 3, bi = (wg >> 3) & 15, b = wg >> 7;

  for (int o = t; o < 2340; o += 256) red_s[o] = 0.f;

  for (int o = t; o < 288; o += 256) {
    int lc = o >> 4, f4i = o & 15;
    int ci = min(max(bi - 1 + lc / 6, 0), 15);
    int cj = min(max(sx * 4 - 1 + lc % 6, 0), 15);
    float4 v = *(const float4*)(cent + (((b << 8) + ci * 16 + cj) << 6) + f4i * 4);
    *(float4*)&cent_s[lc * 68 + f4i * 4] = v;
  }
  __syncthreads();
  if (t < 144) {
    int lc = t >> 3, pt = t & 7;
    float s = 0.f;
#pragma unroll
    for (int m = 0; m < 8; m++) { float v = cent_s[lc * 68 + pt * 8 + m]; s += v * v; }
    c2p[t] = s;
  }
  __syncthreads();
  if (t < 18) {
    float s = 0.f;
#pragma unroll
    for (int m = 0; m < 8; m++) s += c2p[t * 8 + m];
    c2_s[t] = s;
  }
  __syncthreads();

  int r = t >> 5, g = t & 31;
  int row = bi * 16 + half * 8 + r;
  int col = sx * 64 + g * 2;
  int lb = g >> 3;
  int bjb = sx * 4 + lb;

  int cidx[9];
  float c2k[9];
  int vbits = 0;
#pragma unroll
  for (int k = 0; k < 9; k++) {
    int di = k / 3 - 1, dj = k % 3 - 1;
    int ciu = bi + di, cju = bjb + dj;
    if ((unsigned)ciu < 16u && (unsigned)cju < 16u) vbits |= 1 << k;
    int lidx = (di + 1) * 6 + (lb + 1 + dj);
    cidx[k] = lidx * 68;
    c2k[k] = c2_s[lidx];
  }

  const float* base = x + ((long)(b * 64) << 16) + row * 256 + col;

  float acc0[9], acc1[9];
#pragma unroll
  for (int k = 0; k < 9; k++) { acc0[k] = 0.f; acc1[k] = 0.f; }
#pragma unroll 4
  for (int c = 0; c < 64; c++) {
    float2 xv = *(const float2*)(base + ((long)c << 16));
#pragma unroll
    for (int k = 0; k < 9; k++) {
      float cv = cent_s[cidx[k] + c];
      acc0[k] = fmaf(xv.x, cv, acc0[k]);
      acc1[k] = fmaf(xv.y, cv, acc1[k]);
    }
  }

  float mx0 = -1e30f, mx1 = -1e30f;
#pragma unroll
  for (int k = 0; k < 9; k++) {
    float l0 = 2.f * acc0[k] - c2k[k];
    float l1 = 2.f * acc1[k] - c2k[k];
    bool v = (vbits >> k) & 1;
    acc0[k] = v ? l0 : -1e30f;
    acc1[k] = v ? l1 : -1e30f;
    mx0 = fmaxf(mx0, acc0[k]);
    mx1 = fmaxf(mx1, acc1[k]);
  }
  float s0 = 0.f, s1 = 0.f;
#pragma unroll
  for (int k = 0; k < 9; k++) {
    acc0[k] = __expf(acc0[k] - mx0);
    acc1[k] = __expf(acc1[k] - mx1);
    s0 += acc0[k];
    s1 += acc1[k];
  }
  float rs0 = 1.f / s0, rs1 = 1.f / s1;
#pragma unroll
  for (int k = 0; k < 9; k++) { acc0[k] *= rs0; acc1[k] *= rs1; }

  int lane = t & 63;
  bool desig = (lane & 39) == 0;  // lanes 0,8,16,24

#pragma unroll
  for (int k = 0; k < 9; k++) {
    float w = acc0[k] + acc1[k];
    w += __shfl_xor(w, 1);
    w += __shfl_xor(w, 2);
    w += __shfl_xor(w, 4);
    w += __shfl_xor(w, 32);
    if (desig) atomicAdd(&red_s[2304 + lb * 9 + k], w);
  }
#pragma unroll 2
  for (int c = 0; c < 64; c++) {
    float2 xv = *(const float2*)(base + ((long)c << 16));
#pragma unroll
    for (int k = 0; k < 9; k++) {
      float w = xv.x * acc0[k] + xv.y * acc1[k];
      w += __shfl_xor(w, 1);
      w += __shfl_xor(w, 2);
      w += __shfl_xor(w, 4);
      w += __shfl_xor(w, 32);
      if (desig) atomicAdd(&red_s[(lb * 9 + k) * 64 + c], w);
    }
  }
  __syncthreads();
  for (int o = t; o < 2340; o += 256) {
    if (o < 2304) {
      int lb2 = o / 576, rm = o - lb2 * 576;
      int k = rm >> 6, c = rm & 63;
      int di = k / 3 - 1, dj = k % 3 - 1;
      int ciu = bi + di, cju = sx * 4 + lb2 + dj;
      if ((unsigned)ciu < 16u && (unsigned)cju < 16u)
        atomicAdd(&num[(((b << 8) + ciu * 16 + cju) << 6) + c], red_s[o]);
    } else {
      int idx = o - 2304;
      int lb2 = idx / 9, k = idx - lb2 * 9;
      int di = k / 3 - 1, dj = k % 3 - 1;
      int ciu = bi + di, cju = sx * 4 + lb2 + dj;
      if ((unsigned)ciu < 16u && (unsigned)cju < 16u)
        atomicAdd(&den[(b << 8) + ciu * 16 + cju], red_s[o]);
    }
  }
}

// ---- out: finalize cents (num/den) + affinity for one row + write output ----
// grid 1024 = b(4) x i(256). Writes 256 s x 1KB contiguous per wg.
__global__ __launch_bounds__(256) void k_out(const float* __restrict__ x,
                                             const float* __restrict__ num,
                                             const float* __restrict__ den,
                                             float4* __restrict__ out4) {
  __shared__ float cent_s[48 * 68];   // rows bi-1..bi+1 x 16 cols, stride 68
  __shared__ float den_s[48];
  __shared__ float c2p[384];
  __shared__ float c2_s[48];
  __shared__ float aff_t[9 * 260];    // [k][px], stride 260 (16B-aligned)

  int t = threadIdx.x;
  int wg = blockIdx.x;
  int i = wg & 255, b = wg >> 8;
  int bi = i >> 4;

  if (t < 48) {
    int ci = min(max(bi - 1 + (t >> 4), 0), 15);
    int cj = t & 15;
    den_s[t] = den[(b << 8) + ci * 16 + cj] + 1e-16f;
  }
  __syncthreads();
  for (int o = t; o < 768; o += 256) {  // 48 cents x 16 float4
    int lr = o >> 4, f4i = o & 15;
    int ci = min(max(bi - 1 + (lr >> 4), 0), 15);
    int cj = lr & 15;
    float4 v = *(const float4*)(num + (((b << 8) + ci * 16 + cj) << 6) + f4i * 4);
    float inv = 1.f / den_s[lr];
    v.x *= inv; v.y *= inv; v.z *= inv; v.w *= inv;
    *(float4*)&cent_s[lr * 68 + f4i * 4] = v;
  }
  __syncthreads();
  if (t < 192) {  // hmm: need 384 items; do strided
  }
  for (int o = t; o < 384; o += 256) {
    int lr = o >> 3, pt = o & 7;
    float s = 0.f;
#pragma unroll
    for (int m = 0; m < 8; m++) { float v = cent_s[lr * 68 + pt * 8 + m]; s += v * v; }
    c2p[o] = s;
  }
  __syncthreads();
  if (t < 48) {
    float s = 0.f;
#pragma unroll
    for (int m = 0; m < 8; m++) s += c2p[t * 8 + m];
    c2_s[t] = s;
  }
  __syncthreads();

  // phase 1: pixel (i, j=t) affinity
  int j = t, bj = j >> 4;
  int cidx[9];
  float c2k[9];
  int vbits = 0;
#pragma unroll
  for (int k = 0; k < 9; k++) {
    int di = k / 3 - 1, dj = k % 3 - 1;
    int ciu = bi + di, cju = bj + dj;
    if ((unsigned)ciu < 16u && (unsigned)cju < 16u) vbits |= 1 << k;
    int lidx = (di + 1) * 16 + min(max(cju, 0), 15);
    cidx[k] = lidx * 68;
    c2k[k] = c2_s[lidx];
  }
  const float* base = x + ((long)(b * 64) << 16) + (i << 8) + j;
  float acc[9];
#pragma unroll
  for (int k = 0; k < 9; k++) acc[k] = 0.f;
#pragma unroll 4
  for (int c = 0; c < 64; c++) {
    float xv = base[(long)c << 16];
#pragma unroll
    for (int k = 0; k < 9; k++) acc[k] = fmaf(xv, cent_s[cidx[k] + c], acc[k]);
  }
  float mx = -1e30f;
#pragma unroll
  for (int k = 0; k < 9; k++) {
    float l = 2.f * acc[k] - c2k[k];
    acc[k] = ((vbits >> k) & 1) ? l : -1e30f;
    mx = fmaxf(mx, acc[k]);
  }
  float sum = 0.f;
#pragma unroll
  for (int k = 0; k < 9; k++) {
    acc[k] = __expf(acc[k] - mx);
    sum += acc[k];
  }
  float rs = 1.f / sum;
#pragma unroll
  for (int k = 0; k < 9; k++) aff_t[k * 260 + j] = acc[k] * rs;
  __syncthreads();

  // phase B: stream out[b][s][i][0..255] for all 256 s (wave = one s-row)
  float4* obase = out4 + ((long)(b << 8) << 14) + (i << 6) + (t & 63);
  int j4 = t & 63;
  int w = t >> 6;
#pragma unroll 4
  for (int m = 0; m < 64; m++) {
    int s = (m << 2) | w;
    float4 v = make_float4(0.f, 0.f, 0.f, 0.f);
    int di = (s >> 4) - bi;
    if ((unsigned)(di + 1) <= 2u) {
      int dj = (s & 15) - (j4 >> 2);
      if ((unsigned)(dj + 1) <= 2u) {
        int k = (di + 1) * 3 + dj + 1;
        v = *(const float4*)&aff_t[k * 260 + (j4 << 2)];
      }
    }
    obase[(long)s << 14] = v;
  }
}

extern "C" void kernel_launch(void* const* d_in, const int* in_sizes, int n_in,
                              void* d_out, int out_size, void* d_ws, size_t ws_size,
                              hipStream_t stream) {
  const float* x = (const float*)d_in[0];
  float* out = (float*)d_out;
  float* ws = (float*)d_ws;

  float* num   = ws;
  float* den   = ws + 65536;
  float* cent0 = ws + 66560;

  k_init<<<1024, 256, 0, stream>>>(x, cent0, (float4*)ws);
  k_stat<<<512, 256, 0, stream>>>(x, cent0, num, den);
  k_out<<<1024, 256, 0, stream>>>(x, num, den, (float4*)out);
}